// Round 1
// baseline (166.653 us; speedup 1.0000x reference)
//
#include <hip/hip_runtime.h>

typedef __attribute__((ext_vector_type(8))) __bf16 bf16x8;
typedef __attribute__((ext_vector_type(4))) float f32x4;

constexpr float NEG = 1000000000000.0f;  // NEG_INF

static __device__ __forceinline__ unsigned short f2bf(float f) {
    unsigned int u = __float_as_uint(f);
    u += 0x7FFFu + ((u >> 16) & 1u);   // round-to-nearest-even
    return (unsigned short)(u >> 16);
}

// ---------------- prep kernels ----------------

__global__ __launch_bounds__(256) void k_convX(const float* __restrict__ X,
                                               unsigned short* __restrict__ Xb, int n4) {
    int idx = blockIdx.x * 256 + threadIdx.x;
    const int stride = gridDim.x * 256;
    for (; idx < n4; idx += stride) {
        float4 v = reinterpret_cast<const float4*>(X)[idx];
        ushort4 o;
        o.x = f2bf(v.x); o.y = f2bf(v.y); o.z = f2bf(v.z); o.w = f2bf(v.w);
        reinterpret_cast<ushort4*>(Xb)[idx] = o;
    }
}

// W [768][1152] f32  ->  WT [1152][768] bf16
__global__ __launch_bounds__(256) void k_transW(const float* __restrict__ W,
                                                unsigned short* __restrict__ WT) {
    __shared__ __align__(16) unsigned short T[64][72];
    const int k0 = blockIdx.x * 64;
    const int c0 = blockIdx.y * 64;
    const int tid = threadIdx.x;
    const int r = tid >> 2;
    const int q = tid & 3;
    const float* src = W + (k0 + r) * 1152 + c0 + q * 16;
#pragma unroll
    for (int j = 0; j < 16; ++j)
        T[q * 16 + j][r] = f2bf(src[j]);
    __syncthreads();
    unsigned short* dst = WT + (c0 + r) * 768 + k0 + q * 16;
    *reinterpret_cast<uint4*>(dst)     = *reinterpret_cast<const uint4*>(&T[r][q * 16]);
    *reinterpret_cast<uint4*>(dst + 8) = *reinterpret_cast<const uint4*>(&T[r][q * 16 + 8]);
}

// sin/cos tables [1024][32], double-precision generation
__global__ __launch_bounds__(256) void k_sincos(float* __restrict__ ct, float* __restrict__ st) {
    int idx = blockIdx.x * 256 + threadIdx.x;   // 0..32767
    int pos = idx >> 5, i = idx & 31;
    double inv = exp(-9.210340371976184 * (double)(2 * i) / 64.0);  // 10000^(-2i/64)
    double ang = (double)pos * inv;
    ct[idx] = (float)cos(ang);
    st[idx] = (float)sin(ang);
}

// ---------------- projection + RoPE ----------------
// OUT = Xb(8192x768) @ W(768x1152) + b ; per 128-col group = one ent h:
// cols 0..63 -> Q dims, 64..127 -> K dims; RoPE applied; bf16 out.
__global__ __launch_bounds__(256) void k_proj(const unsigned short* __restrict__ Xb,
                                              const unsigned short* __restrict__ WT,
                                              const float* __restrict__ bias,
                                              const float* __restrict__ ct,
                                              const float* __restrict__ st,
                                              unsigned short* __restrict__ Qb,
                                              unsigned short* __restrict__ Kb) {
    __shared__ __align__(16) unsigned short As[128][40];
    __shared__ __align__(16) unsigned short Bs[128][40];
    const int tid = threadIdx.x;
    const int lane = tid & 63;
    const int w = tid >> 6;
    const int wr = w >> 1, wc = w & 1;
    const int m0 = blockIdx.x * 128;
    const int h  = blockIdx.y;           // ent index; c0 = h*128
    const int c0 = h * 128;

    const int sr = tid >> 1;             // staging row 0..127
    const int sseg = (tid & 1) * 16;     // 0 / 16 (elements)
    const int l15 = lane & 15;
    const int kfr = (lane >> 4) * 8;

    f32x4 acc[4][4] = {};

    for (int kt = 0; kt < 24; ++kt) {
        const int k0 = kt * 32;
        __syncthreads();
        const uint4* xs = reinterpret_cast<const uint4*>(Xb + (m0 + sr) * 768 + k0 + sseg);
        uint4 x0 = xs[0], x1 = xs[1];
        const uint4* wsrc = reinterpret_cast<const uint4*>(WT + (c0 + sr) * 768 + k0 + sseg);
        uint4 w0 = wsrc[0], w1 = wsrc[1];
        *reinterpret_cast<uint4*>(&As[sr][sseg])     = x0;
        *reinterpret_cast<uint4*>(&As[sr][sseg + 8]) = x1;
        *reinterpret_cast<uint4*>(&Bs[sr][sseg])     = w0;
        *reinterpret_cast<uint4*>(&Bs[sr][sseg + 8]) = w1;
        __syncthreads();

        bf16x8 a[4], bfr[4];
#pragma unroll
        for (int mi = 0; mi < 4; ++mi)
            a[mi] = *reinterpret_cast<const bf16x8*>(&As[wr * 64 + mi * 16 + l15][kfr]);
#pragma unroll
        for (int ni = 0; ni < 4; ++ni)
            bfr[ni] = *reinterpret_cast<const bf16x8*>(&Bs[wc * 64 + ni * 16 + l15][kfr]);
#pragma unroll
        for (int mi = 0; mi < 4; ++mi)
#pragma unroll
            for (int ni = 0; ni < 4; ++ni)
                acc[mi][ni] = __builtin_amdgcn_mfma_f32_16x16x32_bf16(a[mi], bfr[ni], acc[mi][ni], 0, 0, 0);
    }

    // epilogue: bias + RoPE + scatter to Qb/Kb
#pragma unroll
    for (int mi = 0; mi < 4; ++mi) {
        const int rowb = m0 + wr * 64 + mi * 16 + ((lane >> 4) << 2);
#pragma unroll
        for (int ni = 0; ni < 4; ++ni) {
            const int c128 = wc * 64 + ni * 16 + l15;
            const float bv = bias[c0 + c128];
            const int isK = c128 >> 6;
            const int d = c128 & 63;
            const int fi = d >> 1;
            unsigned short* dst0 = isK ? Kb : Qb;
#pragma unroll
            for (int r = 0; r < 4; ++r) {
                const int grow = rowb + r;
                const int bb = grow >> 10;
                const int s = grow & 1023;
                float v = acc[mi][ni][r] + bv;
                float p = __shfl_xor(v, 1);
                const float cv = ct[s * 32 + fi];
                const float sv = st[s * 32 + fi];
                float o = (d & 1) ? (v * cv + p * sv) : (v * cv - p * sv);
                dst0[(((bb * 9 + h) * 1024 + s) << 6) + d] = f2bf(o);
            }
        }
    }
}

// ---------------- scores: per (b,h) Q @ K^T + mask ----------------
__global__ __launch_bounds__(256) void k_score(const unsigned short* __restrict__ Qb,
                                               const unsigned short* __restrict__ Kb,
                                               const float* __restrict__ pmask,
                                               float* __restrict__ out) {
    const int bh = blockIdx.y;
    const int bidx = bh / 9;
    const int tm = blockIdx.x >> 3, tn = blockIdx.x & 7;
    const int m0 = tm << 7, n0 = tn << 7;
    const int tid = threadIdx.x;
    float* outb = out + (long long)bh * 1048576;
    const float* pm = pmask + bidx * 1024;

    if (n0 + 127 < m0) {
        // fully causal-masked tile: dot*pm is negligible vs threshold; exact mask arithmetic
        const int r = tid >> 1;
        const int half = (tid & 1) * 64;
        float4* dst = reinterpret_cast<float4*>(outb + (long long)(m0 + r) * 1024 + n0 + half);
        const float4* pmv = reinterpret_cast<const float4*>(pm + n0 + half);
#pragma unroll
        for (int v = 0; v < 16; ++v) {
            float4 p = pmv[v];
            float4 o;
            o.x = (-(1.0f - p.x) * NEG - NEG) * 0.125f;
            o.y = (-(1.0f - p.y) * NEG - NEG) * 0.125f;
            o.z = (-(1.0f - p.z) * NEG - NEG) * 0.125f;
            o.w = (-(1.0f - p.w) * NEG - NEG) * 0.125f;
            dst[v] = o;
        }
        return;
    }

    const int lane = tid & 63;
    const int w = tid >> 6;
    const int wr = w >> 1, wc = w & 1;
    const int l15 = lane & 15;
    const int kfr = (lane >> 4) * 8;
    const unsigned short* qb = Qb + bh * 65536;
    const unsigned short* kb = Kb + bh * 65536;

    bf16x8 a[4][2], b[4][2];
#pragma unroll
    for (int mi = 0; mi < 4; ++mi)
#pragma unroll
        for (int kk = 0; kk < 2; ++kk)
            a[mi][kk] = *reinterpret_cast<const bf16x8*>(qb + (m0 + wr * 64 + mi * 16 + l15) * 64 + kk * 32 + kfr);
#pragma unroll
    for (int ni = 0; ni < 4; ++ni)
#pragma unroll
        for (int kk = 0; kk < 2; ++kk)
            b[ni][kk] = *reinterpret_cast<const bf16x8*>(kb + (n0 + wc * 64 + ni * 16 + l15) * 64 + kk * 32 + kfr);

    f32x4 acc[4][4] = {};
#pragma unroll
    for (int mi = 0; mi < 4; ++mi)
#pragma unroll
        for (int ni = 0; ni < 4; ++ni) {
            acc[mi][ni] = __builtin_amdgcn_mfma_f32_16x16x32_bf16(a[mi][0], b[ni][0], acc[mi][ni], 0, 0, 0);
            acc[mi][ni] = __builtin_amdgcn_mfma_f32_16x16x32_bf16(a[mi][1], b[ni][1], acc[mi][ni], 0, 0, 0);
        }

    float pmv[4];
#pragma unroll
    for (int ni = 0; ni < 4; ++ni)
        pmv[ni] = pm[n0 + wc * 64 + ni * 16 + l15];

#pragma unroll
    for (int mi = 0; mi < 4; ++mi) {
        const int rowb = m0 + wr * 64 + mi * 16 + ((lane >> 4) << 2);
#pragma unroll
        for (int ni = 0; ni < 4; ++ni) {
            const int col = n0 + wc * 64 + ni * 16 + l15;
#pragma unroll
            for (int r = 0; r < 4; ++r) {
                const int row = rowb + r;
                const float dot = acc[mi][ni][r];
                float val = (dot * pmv[ni] - (1.0f - pmv[ni]) * NEG - ((col < row) ? NEG : 0.0f)) * 0.125f;
                outb[(long long)row * 1024 + col] = val;
            }
        }
    }
}

extern "C" void kernel_launch(void* const* d_in, const int* in_sizes, int n_in,
                              void* d_out, int out_size, void* d_ws, size_t ws_size,
                              hipStream_t stream) {
    const float* X    = (const float*)d_in[0];
    const float* pm   = (const float*)d_in[1];
    const float* W    = (const float*)d_in[2];
    const float* bias = (const float*)d_in[3];
    char* ws = (char*)d_ws;
    unsigned short* Xb = (unsigned short*)(ws + 0);          // 8192x768 bf16
    unsigned short* WT = (unsigned short*)(ws + 12582912);   // 1152x768 bf16
    unsigned short* Qb = (unsigned short*)(ws + 14352384);   // 72x1024x64 bf16
    unsigned short* Kb = (unsigned short*)(ws + 23789568);   // 72x1024x64 bf16
    float* ct = (float*)(ws + 33226752);                     // 1024x32 f32
    float* st = (float*)(ws + 33357824);                     // 1024x32 f32
    float* out = (float*)d_out;

    hipLaunchKernelGGL(k_convX, dim3(2048), dim3(256), 0, stream, X, Xb, 6291456 / 4);
    hipLaunchKernelGGL(k_transW, dim3(12, 18), dim3(256), 0, stream, W, WT);
    hipLaunchKernelGGL(k_sincos, dim3(128), dim3(256), 0, stream, ct, st);
    hipLaunchKernelGGL(k_proj, dim3(64, 9), dim3(256), 0, stream, Xb, WT, bias, ct, st, Qb, Kb);
    hipLaunchKernelGGL(k_score, dim3(64, 72), dim3(256), 0, stream, Qb, Kb, pm, out);
}